// Round 12
// baseline (303.448 us; speedup 1.0000x reference)
//
#include <hip/hip_runtime.h>
#include <math.h>

typedef __attribute__((ext_vector_type(8))) short s16x8;
typedef __attribute__((ext_vector_type(4))) float f32x4;

#define MFMA(a,b,c) __builtin_amdgcn_mfma_f32_16x16x32_bf16((a),(b),(c),0,0,0)

__device__ __forceinline__ unsigned short f2bf(float f){
    unsigned u = __builtin_bit_cast(unsigned, f);
    u += 0x7FFFu + ((u >> 16) & 1u);
    return (unsigned short)(u >> 16);
}
__device__ __forceinline__ float bf2f(unsigned short u){
    return __builtin_bit_cast(float, ((unsigned)u) << 16);
}
__device__ __forceinline__ float4 fma4(float s, float4 a, float4 c){
    c.x = fmaf(s, a.x, c.x); c.y = fmaf(s, a.y, c.y);
    c.z = fmaf(s, a.z, c.z); c.w = fmaf(s, a.w, c.w);
    return c;
}
__device__ __forceinline__ unsigned pk_bf16(float lo, float hi){
    return (unsigned)f2bf(lo) | ((unsigned)f2bf(hi) << 16);
}
__device__ __forceinline__ void gld_lds16(const void* g, void* l){
    __builtin_amdgcn_global_load_lds(
        (const __attribute__((address_space(1))) void*)g,
        (__attribute__((address_space(3))) void*)l, 16, 0, 0);
}

// ---------------------------------------------------------------------------
// f32 -> bf16 pre-conversion for query / in_w / out_w (one launch).
// ---------------------------------------------------------------------------
__global__ __launch_bounds__(256) void cvt3(
    const float* __restrict__ s0, unsigned short* __restrict__ d0, int n0,
    const float* __restrict__ s1, unsigned short* __restrict__ d1, int n1,
    const float* __restrict__ s2, unsigned short* __restrict__ d2, int n2)
{
    const int i = blockIdx.x*256 + threadIdx.x;
    const float* s; unsigned short* d; int j;
    if (i < n0){ s = s0; d = d0; j = i; }
    else if (i < n0 + n1){ s = s1; d = d1; j = i - n0; }
    else if (i < n0 + n1 + n2){ s = s2; d = d2; j = i - n0 - n1; }
    else return;
    float4 a = *(const float4*)(s + (size_t)j*8);
    float4 b = *(const float4*)(s + (size_t)j*8 + 4);
    alignas(16) unsigned short t[8] = {
        f2bf(a.x), f2bf(a.y), f2bf(a.z), f2bf(a.w),
        f2bf(b.x), f2bf(b.y), f2bf(b.z), f2bf(b.w) };
    *(s16x8*)(d + (size_t)j*8) = *(const s16x8*)t;
}

// ---------------------------------------------------------------------------
// QKV projection, bf16 inputs, DOUBLE-buffered global_load_lds staging with
// counted vmcnt(8): step c+1's 8 DMAs stay in flight through step c's MFMA.
// Raw s_barrier (no vmcnt(0) drain). 64 KB LDS (residency already capped at
// ~2 blocks/CU by grid size, so no occupancy loss).
// ---------------------------------------------------------------------------
__global__ __launch_bounds__(256) void gemm_qkv_bf16(
    const unsigned short* __restrict__ X,   // [4096][768] bf16
    const unsigned short* __restrict__ W,   // [2304][768] bf16
    const float* __restrict__ bvec,
    unsigned short* __restrict__ qs,
    unsigned short* __restrict__ kb,
    unsigned short* __restrict__ vtb)
{
    __shared__ __align__(16) unsigned short Al[2][128*64];
    __shared__ __align__(16) unsigned short Bl[2][128*64];
    const int tid = threadIdx.x;
    const int m0 = blockIdx.y*128, n0 = blockIdx.x*128;
    const int w = tid>>6, lane = tid&63, g = lane>>4, cc = lane&15;
    const int arow_base = (w>>1)*64, brow_base = (w&1)*64;
    const int srowb = w*32 + (lane>>3);   // staging row for inst i: +i*8
    const int gl = lane&7;

    f32x4 acc[4][4];
#pragma unroll
    for (int i=0;i<4;i++)
#pragma unroll
        for (int j=0;j<4;j++) acc[i][j] = (f32x4){0.f,0.f,0.f,0.f};

    #define GSTAGE(buf_, kt_) do {                                          \
        _Pragma("unroll")                                                   \
        for (int i_=0;i_<4;i_++){                                           \
            const int ra_ = srowb + i_*8;                                   \
            gld_lds16(X + (size_t)(m0+ra_)*768 + (kt_) + ((gl ^ (ra_&7))<<3), \
                      &Al[buf_][(w*32 + i_*8)*64]);                         \
            gld_lds16(W + (size_t)(n0+ra_)*768 + (kt_) + ((gl ^ (ra_&7))<<3), \
                      &Bl[buf_][(w*32 + i_*8)*64]);                         \
        }                                                                   \
    } while(0)

    GSTAGE(0, 0);
    for (int step = 0; step < 12; ++step){
        const int buf = step & 1;
        if (step < 11){
            GSTAGE(buf^1, (step+1)*64);
            asm volatile("s_waitcnt vmcnt(8)" ::: "memory");
        } else {
            asm volatile("s_waitcnt vmcnt(0)" ::: "memory");
        }
        __builtin_amdgcn_s_barrier();      // all waves' buf DMAs landed
        __builtin_amdgcn_sched_barrier(0);
#pragma unroll
        for (int ks=0;ks<2;ks++){
            s16x8 af[4], bfr[4];
#pragma unroll
            for (int i=0;i<4;i++){
                const int ra = arow_base + i*16 + cc;
                const int rb = brow_base + i*16 + cc;
                af[i]  = *(const s16x8*)&Al[buf][ra*64 + (((ks*4+g) ^ (ra&7))<<3)];
                bfr[i] = *(const s16x8*)&Bl[buf][rb*64 + (((ks*4+g) ^ (rb&7))<<3)];
            }
#pragma unroll
            for (int i=0;i<4;i++)
#pragma unroll
                for (int j=0;j<4;j++)
                    acc[i][j] = MFMA(af[i], bfr[j], acc[i][j]);
        }
        asm volatile("s_waitcnt lgkmcnt(0)" ::: "memory");
        __builtin_amdgcn_s_barrier();      // reads done before buf overwrite
    }
    #undef GSTAGE

    const int region = blockIdx.x / 6;   // 0:q 1:k 2:v
#pragma unroll
    for (int j=0;j<4;j++){
        const int n = n0 + brow_base + j*16 + cc;
        const float bb = bvec[n];
        const int nn = n - region*768;
        const int h = nn >> 6, d = nn & 63;
        if (region == 0){
#pragma unroll
            for (int i=0;i<4;i++){
                const int m = m0 + arow_base + i*16 + g*4;
                const int bq = m >> 10, t = m & 1023;
                unsigned short* dst = qs + ((size_t)(bq*12+h)*1024 + t)*64 + d;
#pragma unroll
                for (int r=0;r<4;r++)
                    dst[(size_t)r*64] = f2bf((acc[i][j][r] + bb)*0.125f);
            }
        } else if (region == 1){
#pragma unroll
            for (int i=0;i<4;i++){
                const int m = m0 + arow_base + i*16 + g*4;
                const int bq = m >> 10, t = m & 1023;
                unsigned short* dst = kb + ((size_t)(bq*12+h)*1024 + t)*64 + d;
#pragma unroll
                for (int r=0;r<4;r++)
                    dst[(size_t)r*64] = f2bf(acc[i][j][r] + bb);
            }
        } else {
#pragma unroll
            for (int i=0;i<4;i++){
                const int m = m0 + arow_base + i*16 + g*4;
                const int bq = m >> 10, t = m & 1023;
                ushort4 pk;
                pk.x = f2bf(acc[i][j][0] + bb);
                pk.y = f2bf(acc[i][j][1] + bb);
                pk.z = f2bf(acc[i][j][2] + bb);
                pk.w = f2bf(acc[i][j][3] + bb);
                *(ushort4*)&vtb[((size_t)(bq*12+h)*64 + d)*1024 + t] = pk;
            }
        }
    }
}

// ---------------------------------------------------------------------------
// Output projection: out = o(bf16) @ wo(bf16)^T + b, f32 out. Same
// double-buffered counted-vmcnt structure (192 blocks -> latency-bound).
// ---------------------------------------------------------------------------
__global__ __launch_bounds__(256) void gemm_obf_bf16(
    const unsigned short* __restrict__ X,   // [4096][768] bf16
    const unsigned short* __restrict__ W,   // [768][768] bf16
    const float* __restrict__ bvec, float* __restrict__ out)
{
    __shared__ __align__(16) unsigned short Al[2][128*64];
    __shared__ __align__(16) unsigned short Bl[2][128*64];
    const int tid = threadIdx.x;
    const int m0 = blockIdx.y*128, n0 = blockIdx.x*128;
    const int w = tid>>6, lane = tid&63, g = lane>>4, cc = lane&15;
    const int arow_base = (w>>1)*64, brow_base = (w&1)*64;
    const int srowb = w*32 + (lane>>3);
    const int gl = lane&7;

    f32x4 acc[4][4];
#pragma unroll
    for (int i=0;i<4;i++)
#pragma unroll
        for (int j=0;j<4;j++) acc[i][j] = (f32x4){0.f,0.f,0.f,0.f};

    #define GSTAGE(buf_, kt_) do {                                          \
        _Pragma("unroll")                                                   \
        for (int i_=0;i_<4;i_++){                                           \
            const int ra_ = srowb + i_*8;                                   \
            gld_lds16(X + (size_t)(m0+ra_)*768 + (kt_) + ((gl ^ (ra_&7))<<3), \
                      &Al[buf_][(w*32 + i_*8)*64]);                         \
            gld_lds16(W + (size_t)(n0+ra_)*768 + (kt_) + ((gl ^ (ra_&7))<<3), \
                      &Bl[buf_][(w*32 + i_*8)*64]);                         \
        }                                                                   \
    } while(0)

    GSTAGE(0, 0);
    for (int step = 0; step < 12; ++step){
        const int buf = step & 1;
        if (step < 11){
            GSTAGE(buf^1, (step+1)*64);
            asm volatile("s_waitcnt vmcnt(8)" ::: "memory");
        } else {
            asm volatile("s_waitcnt vmcnt(0)" ::: "memory");
        }
        __builtin_amdgcn_s_barrier();
        __builtin_amdgcn_sched_barrier(0);
#pragma unroll
        for (int ks=0;ks<2;ks++){
            s16x8 af[4], bfr[4];
#pragma unroll
            for (int i=0;i<4;i++){
                const int ra = arow_base + i*16 + cc;
                const int rb = brow_base + i*16 + cc;
                af[i]  = *(const s16x8*)&Al[buf][ra*64 + (((ks*4+g) ^ (ra&7))<<3)];
                bfr[i] = *(const s16x8*)&Bl[buf][rb*64 + (((ks*4+g) ^ (rb&7))<<3)];
            }
#pragma unroll
            for (int i=0;i<4;i++)
#pragma unroll
                for (int j=0;j<4;j++)
                    acc[i][j] = MFMA(af[i], bfr[j], acc[i][j]);
        }
        asm volatile("s_waitcnt lgkmcnt(0)" ::: "memory");
        __builtin_amdgcn_s_barrier();
    }
    #undef GSTAGE

#pragma unroll
    for (int j=0;j<4;j++){
        const int n = n0 + brow_base + j*16 + cc;
        const float bb = bvec[n];
#pragma unroll
        for (int i=0;i<4;i++){
            const int mb = m0 + arow_base + i*16 + g*4;
#pragma unroll
            for (int r=0;r<4;r++)
                out[(size_t)(mb+r)*768 + n] = acc[i][j][r] + bb;
        }
    }
}

// ---------------------------------------------------------------------------
// Flash attention (unchanged from round 11 best).
// ---------------------------------------------------------------------------
__global__ __launch_bounds__(64, 1) void attn_mfma(
    const unsigned short* __restrict__ qs,   // [48][1024][64] bf16 (q*0.125)
    const unsigned short* __restrict__ kbf,  // [48][1024][64] bf16
    const unsigned short* __restrict__ vtf,  // [48][64][1024] bf16
    const float* __restrict__ kdyn,          // [48*1024][4][1024]
    const int*   __restrict__ kpm,           // [4][1024]
    const float* __restrict__ bias,          // [48][1024][1024]
    const float* __restrict__ red_w,         // [4][64]
    const float* __restrict__ red_b,         // [4]
    unsigned short* __restrict__ o)          // [4096][768] bf16
{
    __shared__ __align__(16) float kdL[2][2048];   // 2 x 8 KB
    __shared__ __align__(16) float bL[2][512];     // 2 x 2 KB

    const int lane = threadIdx.x & 63;
    const int bh = blockIdx.x, qt = blockIdx.y;
    const int b = bh / 12, h = bh % 12;
    const int t0 = qt*16;
    const int g = lane>>4, cc = lane&15;
    const int tq = t0 + cc;

    const unsigned short* qrow = qs + ((size_t)bh*1024 + tq)*64;
    s16x8 qf[2];
    qf[0] = *(const s16x8*)(qrow + g*8);
    qf[1] = *(const s16x8*)(qrow + 32 + g*8);

    float qred[4];
    {
        float pr[4] = {0.f,0.f,0.f,0.f};
#pragma unroll
        for (int ks=0; ks<2; ks++){
#pragma unroll
            for (int r=0;r<4;r++){
                float4 w0 = *(const float4*)(red_w + r*64 + 32*ks + 8*g);
                float4 w1 = *(const float4*)(red_w + r*64 + 32*ks + 8*g + 4);
                pr[r] += bf2f((unsigned short)qf[ks][0])*w0.x + bf2f((unsigned short)qf[ks][1])*w0.y
                       + bf2f((unsigned short)qf[ks][2])*w0.z + bf2f((unsigned short)qf[ks][3])*w0.w
                       + bf2f((unsigned short)qf[ks][4])*w1.x + bf2f((unsigned short)qf[ks][5])*w1.y
                       + bf2f((unsigned short)qf[ks][6])*w1.z + bf2f((unsigned short)qf[ks][7])*w1.w;
            }
        }
#pragma unroll
        for (int r=0;r<4;r++){
            pr[r] += __shfl_xor(pr[r], 16);
            pr[r] += __shfl_xor(pr[r], 32);
            qred[r] = pr[r]*8.f + red_b[r];
        }
    }

    f32x4 accO[4];
#pragma unroll
    for (int i=0;i<4;i++) accO[i] = (f32x4){0.f,0.f,0.f,0.f};
    float m_ = -1e30f, l_ = 0.f;

    const unsigned short* kcb = kbf + (size_t)bh*1024*64;
    const unsigned short* vcb = vtf + ((size_t)bh*64 + cc)*1024;
    const int* mp = kpm + b*1024 + 4*g;
    const size_t kd_row = (size_t)(bh*1024 + t0);

    const int r8_ = lane>>3, g8_ = lane&7;

    #define STAGE(buf_, c_) do {                                                  \
        const int s0_ = (c_)*32;                                                  \
        _Pragma("unroll")                                                         \
        for (int i_=0;i_<8;i_++){            /* kdyn rows rr=8i+r8 */             \
            const int rr_ = 8*i_ + r8_;                                           \
            const int t_ = rr_>>2, r_ = rr_&3;                                    \
            gld_lds16(kdyn + (kd_row + t_)*4096 + (size_t)r_*1024 + s0_           \
                          + ((g8_ ^ (t_&7))<<2),                                  \
                      &kdL[buf_][i_*256]);                                        \
        }                                                                         \
        _Pragma("unroll")                                                         \
        for (int i_=0;i_<2;i_++){            /* bias rows t=8i+r8 */              \
            const int t_ = 8*i_ + r8_;                                            \
            gld_lds16(bias + (kd_row + t_)*1024 + s0_ + ((g8_ ^ (t_&7))<<2),      \
                      &bL[buf_][i_*256]);                                         \
        }                                                                         \
    } while(0)

    STAGE(0, 0);

    const float NINF = -__builtin_inff();
    const int srcA = ((g&1)<<5) + cc;
    const int srcB = srcA + 16;
    const bool hi_half = (g>>1) != 0;

#pragma unroll 1
    for (int c = 0; c < 32; ++c) {
        const int buf = c & 1;
        const int s0 = c*32;

        s16x8 kfr[2][2];
#pragma unroll
        for (int sq=0;sq<2;sq++){
            const unsigned short* kp = kcb + (size_t)(s0 + 16*sq + cc)*64 + g*8;
            kfr[sq][0] = *(const s16x8*)(kp);
            kfr[sq][1] = *(const s16x8*)(kp + 32);
        }
        s16x8 vfr[4];
#pragma unroll
        for (int dq=0;dq<4;dq++)
            vfr[dq] = *(const s16x8*)(vcb + (size_t)dq*16*1024 + s0 + 8*g);
        int4 mm0 = *(const int4*)(mp + s0);
        int4 mm1 = *(const int4*)(mp + s0 + 16);
        __builtin_amdgcn_sched_barrier(0);

        if (c < 31){
            STAGE(buf^1, c+1);
            asm volatile("s_waitcnt vmcnt(10)" ::: "memory");
        } else {
            asm volatile("s_waitcnt vmcnt(0)" ::: "memory");
        }
        __builtin_amdgcn_sched_barrier(0);

        float4 dyn[2];
#pragma unroll
        for (int sq=0;sq<2;sq++){
            const int slot = ((4*sq + g) ^ (cc&7)) << 2;
            float4 dv = *(const float4*)&bL[buf][cc*32 + slot];
            dv = fma4(qred[0], *(const float4*)&kdL[buf][(cc*4+0)*32 + slot], dv);
            dv = fma4(qred[1], *(const float4*)&kdL[buf][(cc*4+1)*32 + slot], dv);
            dv = fma4(qred[2], *(const float4*)&kdL[buf][(cc*4+2)*32 + slot], dv);
            dv = fma4(qred[3], *(const float4*)&kdL[buf][(cc*4+3)*32 + slot], dv);
            const int4 m4 = sq ? mm1 : mm0;
            dv.x = m4.x ? NINF : dv.x;
            dv.y = m4.y ? NINF : dv.y;
            dv.z = m4.z ? NINF : dv.z;
            dv.w = m4.w ? NINF : dv.w;
            dyn[sq] = dv;
        }

        f32x4 sc[2];
        __builtin_amdgcn_s_setprio(1);
#pragma unroll
        for (int sq=0;sq<2;sq++){
            f32x4 z = (f32x4){0.f,0.f,0.f,0.f};
            z = MFMA(kfr[sq][0], qf[0], z);
            z = MFMA(kfr[sq][1], qf[1], z);
            sc[sq] = z;
        }
        __builtin_amdgcn_s_setprio(0);

        float v[8];
#pragma unroll
        for (int sq=0;sq<2;sq++){
            v[sq*4+0] = sc[sq][0] + dyn[sq].x;
            v[sq*4+1] = sc[sq][1] + dyn[sq].y;
            v[sq*4+2] = sc[sq][2] + dyn[sq].z;
            v[sq*4+3] = sc[sq][3] + dyn[sq].w;
        }
        float mx = v[0];
#pragma unroll
        for (int i=1;i<8;i++) mx = fmaxf(mx, v[i]);
        mx = fmaxf(mx, __shfl_xor(mx, 16));
        mx = fmaxf(mx, __shfl_xor(mx, 32));
        const float mn = fmaxf(m_, mx);
        float ps = 0.f;
#pragma unroll
        for (int i=0;i<8;i++){ v[i] = __expf(v[i]-mn); ps += v[i]; }
        ps += __shfl_xor(ps, 16);
        ps += __shfl_xor(ps, 32);
        const float scl = __expf(m_-mn);
        m_ = mn; l_ = l_*scl + ps;

        unsigned U[4] = { pk_bf16(v[0],v[1]), pk_bf16(v[2],v[3]),
                          pk_bf16(v[4],v[5]), pk_bf16(v[6],v[7]) };
        unsigned a0 = (unsigned)__shfl((int)U[0], srcA);
        unsigned a1 = (unsigned)__shfl((int)U[1], srcA);
        unsigned a2 = (unsigned)__shfl((int)U[2], srcA);
        unsigned a3 = (unsigned)__shfl((int)U[3], srcA);
        unsigned b0 = (unsigned)__shfl((int)U[0], srcB);
        unsigned b1 = (unsigned)__shfl((int)U[1], srcB);
        unsigned b2 = (unsigned)__shfl((int)U[2], srcB);
        unsigned b3 = (unsigned)__shfl((int)U[3], srcB);
        alignas(16) unsigned wv4[4] = { hi_half ? a2 : a0, hi_half ? a3 : a1,
                                        hi_half ? b2 : b0, hi_half ? b3 : b1 };
        s16x8 pa = *(const s16x8*)wv4;

        float sr[4];
#pragma unroll
        for (int r=0;r<4;r++) sr[r] = __shfl(scl, 20*g + r);
#pragma unroll
        for (int dq=0;dq<4;dq++){
            f32x4 a = accO[dq];
            a[0]*=sr[0]; a[1]*=sr[1]; a[2]*=sr[2]; a[3]*=sr[3];
            accO[dq] = a;
        }

        __builtin_amdgcn_s_setprio(1);
#pragma unroll
        for (int dq=0;dq<4;dq++)
            accO[dq] = MFMA(pa, vfr[dq], accO[dq]);
        __builtin_amdgcn_s_setprio(0);
    }
    #undef STAGE

    float linv[4];
#pragma unroll
    for (int r=0;r<4;r++) linv[r] = 1.0f / __shfl(l_, 20*g + r);
#pragma unroll
    for (int dq=0;dq<4;dq++){
#pragma unroll
        for (int r=0;r<4;r++){
            const int t = t0 + 4*g + r;
            o[(size_t)(b*1024 + t)*768 + h*64 + 16*dq + cc] = f2bf(accO[dq][r] * linv[r]);
        }
    }
}

extern "C" void kernel_launch(void* const* d_in, const int* in_sizes, int n_in,
                              void* d_out, int out_size, void* d_ws, size_t ws_size,
                              hipStream_t stream) {
    const float* query = (const float*)d_in[0];
    const float* kdyn  = (const float*)d_in[1];
    const int*   kpm   = (const int*)d_in[2];
    const float* bias  = (const float*)d_in[3];
    const float* in_w  = (const float*)d_in[4];
    const float* in_b  = (const float*)d_in[5];
    const float* red_w = (const float*)d_in[6];
    const float* red_b = (const float*)d_in[7];
    const float* out_w = (const float*)d_in[8];
    const float* out_b = (const float*)d_in[9];
    float* out = (float*)d_out;

    const size_t SEG = (size_t)48*1024*64;           // 3,145,728 elems
    unsigned short* qs  = (unsigned short*)d_ws;
    unsigned short* kb  = qs + SEG;
    unsigned short* vt  = kb + SEG;
    unsigned short* ob  = vt + SEG;                  // [4096][768] bf16
    unsigned short* qb  = ob + SEG;                  // query bf16 [4096][768]
    unsigned short* wqb = qb + SEG;                  // in_w bf16 [2304][768]
    unsigned short* wob = wqb + (size_t)2304*768;    // out_w bf16 [768][768]

    const int n0 = (4096*768)/8;    // 393216
    const int n1 = (2304*768)/8;    // 221184
    const int n2 = (768*768)/8;     //  73728
    cvt3<<<dim3((n0+n1+n2+255)/256), 256, 0, stream>>>(
        query, qb, n0, in_w, wqb, n1, out_w, wob, n2);

    gemm_qkv_bf16<<<dim3(18,32), 256, 0, stream>>>(qb, wqb, in_b, qs, kb, vt);
    attn_mfma<<<dim3(48,64), 64, 0, stream>>>(qs, kb, vt, kdyn, kpm, bias, red_w, red_b, ob);
    gemm_obf_bf16<<<dim3(6,32), 256, 0, stream>>>(ob, wob, out_b, out);
}

// Round 13
// 283.513 us; speedup vs baseline: 1.0703x; 1.0703x over previous
//
#include <hip/hip_runtime.h>
#include <math.h>

typedef __attribute__((ext_vector_type(8))) short s16x8;
typedef __attribute__((ext_vector_type(4))) float f32x4;

#define MFMA(a,b,c) __builtin_amdgcn_mfma_f32_16x16x32_bf16((a),(b),(c),0,0,0)

__device__ __forceinline__ unsigned short f2bf(float f){
    unsigned u = __builtin_bit_cast(unsigned, f);
    u += 0x7FFFu + ((u >> 16) & 1u);
    return (unsigned short)(u >> 16);
}
__device__ __forceinline__ float bf2f(unsigned short u){
    return __builtin_bit_cast(float, ((unsigned)u) << 16);
}
__device__ __forceinline__ float4 fma4(float s, float4 a, float4 c){
    c.x = fmaf(s, a.x, c.x); c.y = fmaf(s, a.y, c.y);
    c.z = fmaf(s, a.z, c.z); c.w = fmaf(s, a.w, c.w);
    return c;
}
__device__ __forceinline__ unsigned pk_bf16(float lo, float hi){
    return (unsigned)f2bf(lo) | ((unsigned)f2bf(hi) << 16);
}
__device__ __forceinline__ void gld_lds16(const void* g, void* l){
    __builtin_amdgcn_global_load_lds(
        (const __attribute__((address_space(1))) void*)g,
        (__attribute__((address_space(3))) void*)l, 16, 0, 0);
}

// ---------------------------------------------------------------------------
// f32 -> bf16 pre-conversion for query / in_w / out_w (one launch).
// ---------------------------------------------------------------------------
__global__ __launch_bounds__(256) void cvt3(
    const float* __restrict__ s0, unsigned short* __restrict__ d0, int n0,
    const float* __restrict__ s1, unsigned short* __restrict__ d1, int n1,
    const float* __restrict__ s2, unsigned short* __restrict__ d2, int n2)
{
    const int i = blockIdx.x*256 + threadIdx.x;
    const float* s; unsigned short* d; int j;
    if (i < n0){ s = s0; d = d0; j = i; }
    else if (i < n0 + n1){ s = s1; d = d1; j = i - n0; }
    else if (i < n0 + n1 + n2){ s = s2; d = d2; j = i - n0 - n1; }
    else return;
    float4 a = *(const float4*)(s + (size_t)j*8);
    float4 b = *(const float4*)(s + (size_t)j*8 + 4);
    alignas(16) unsigned short t[8] = {
        f2bf(a.x), f2bf(a.y), f2bf(a.z), f2bf(a.w),
        f2bf(b.x), f2bf(b.y), f2bf(b.z), f2bf(b.w) };
    *(s16x8*)(d + (size_t)j*8) = *(const s16x8*)t;
}

// ---------------------------------------------------------------------------
// QKV projection, bf16 inputs, m97-style global_load_lds staging (R11 best).
// ---------------------------------------------------------------------------
__global__ __launch_bounds__(256) void gemm_qkv_bf16(
    const unsigned short* __restrict__ X,   // [4096][768] bf16
    const unsigned short* __restrict__ W,   // [2304][768] bf16
    const float* __restrict__ bvec,
    unsigned short* __restrict__ qs,
    unsigned short* __restrict__ kb,
    unsigned short* __restrict__ vtb)
{
    __shared__ __align__(16) unsigned short Al[128*64];
    __shared__ __align__(16) unsigned short Bl[128*64];
    const int tid = threadIdx.x;
    const int m0 = blockIdx.y*128, n0 = blockIdx.x*128;
    const int w = tid>>6, lane = tid&63, g = lane>>4, cc = lane&15;
    const int arow_base = (w>>1)*64, brow_base = (w&1)*64;
    const int srowb = w*32 + (lane>>3);
    const int gl = lane&7;

    f32x4 acc[4][4];
#pragma unroll
    for (int i=0;i<4;i++)
#pragma unroll
        for (int j=0;j<4;j++) acc[i][j] = (f32x4){0.f,0.f,0.f,0.f};

    for (int kt = 0; kt < 768; kt += 64) {
        __syncthreads();
#pragma unroll
        for (int i=0;i<4;i++){
            const int ra = srowb + i*8;
            gld_lds16(X + (size_t)(m0+ra)*768 + kt + ((gl ^ (ra&7))<<3),
                      &Al[(w*32 + i*8)*64]);
            gld_lds16(W + (size_t)(n0+ra)*768 + kt + ((gl ^ (ra&7))<<3),
                      &Bl[(w*32 + i*8)*64]);
        }
        __syncthreads();
#pragma unroll
        for (int ks=0;ks<2;ks++){
            s16x8 af[4], bfr[4];
#pragma unroll
            for (int i=0;i<4;i++){
                const int ra = arow_base + i*16 + cc;
                const int rb = brow_base + i*16 + cc;
                af[i]  = *(const s16x8*)&Al[ra*64 + (((ks*4+g) ^ (ra&7))<<3)];
                bfr[i] = *(const s16x8*)&Bl[rb*64 + (((ks*4+g) ^ (rb&7))<<3)];
            }
#pragma unroll
            for (int i=0;i<4;i++)
#pragma unroll
                for (int j=0;j<4;j++)
                    acc[i][j] = MFMA(af[i], bfr[j], acc[i][j]);
        }
    }

    const int region = blockIdx.x / 6;   // 0:q 1:k 2:v
#pragma unroll
    for (int j=0;j<4;j++){
        const int n = n0 + brow_base + j*16 + cc;
        const float bb = bvec[n];
        const int nn = n - region*768;
        const int h = nn >> 6, d = nn & 63;
        if (region == 0){
#pragma unroll
            for (int i=0;i<4;i++){
                const int m = m0 + arow_base + i*16 + g*4;
                const int bq = m >> 10, t = m & 1023;
                unsigned short* dst = qs + ((size_t)(bq*12+h)*1024 + t)*64 + d;
#pragma unroll
                for (int r=0;r<4;r++)
                    dst[(size_t)r*64] = f2bf((acc[i][j][r] + bb)*0.125f);
            }
        } else if (region == 1){
#pragma unroll
            for (int i=0;i<4;i++){
                const int m = m0 + arow_base + i*16 + g*4;
                const int bq = m >> 10, t = m & 1023;
                unsigned short* dst = kb + ((size_t)(bq*12+h)*1024 + t)*64 + d;
#pragma unroll
                for (int r=0;r<4;r++)
                    dst[(size_t)r*64] = f2bf(acc[i][j][r] + bb);
            }
        } else {
#pragma unroll
            for (int i=0;i<4;i++){
                const int m = m0 + arow_base + i*16 + g*4;
                const int bq = m >> 10, t = m & 1023;
                ushort4 pk;
                pk.x = f2bf(acc[i][j][0] + bb);
                pk.y = f2bf(acc[i][j][1] + bb);
                pk.z = f2bf(acc[i][j][2] + bb);
                pk.w = f2bf(acc[i][j][3] + bb);
                *(ushort4*)&vtb[((size_t)(bq*12+h)*64 + d)*1024 + t] = pk;
            }
        }
    }
}

// ---------------------------------------------------------------------------
// Output projection (R11 best structure).
// ---------------------------------------------------------------------------
__global__ __launch_bounds__(256) void gemm_obf_bf16(
    const unsigned short* __restrict__ X,   // [4096][768] bf16
    const unsigned short* __restrict__ W,   // [768][768] bf16
    const float* __restrict__ bvec, float* __restrict__ out)
{
    __shared__ __align__(16) unsigned short Al[128*64];
    __shared__ __align__(16) unsigned short Bl[128*64];
    const int tid = threadIdx.x;
    const int m0 = blockIdx.y*128, n0 = blockIdx.x*128;
    const int w = tid>>6, lane = tid&63, g = lane>>4, cc = lane&15;
    const int arow_base = (w>>1)*64, brow_base = (w&1)*64;
    const int srowb = w*32 + (lane>>3);
    const int gl = lane&7;

    f32x4 acc[4][4];
#pragma unroll
    for (int i=0;i<4;i++)
#pragma unroll
        for (int j=0;j<4;j++) acc[i][j] = (f32x4){0.f,0.f,0.f,0.f};

    for (int kt = 0; kt < 768; kt += 64) {
        __syncthreads();
#pragma unroll
        for (int i=0;i<4;i++){
            const int ra = srowb + i*8;
            gld_lds16(X + (size_t)(m0+ra)*768 + kt + ((gl ^ (ra&7))<<3),
                      &Al[(w*32 + i*8)*64]);
            gld_lds16(W + (size_t)(n0+ra)*768 + kt + ((gl ^ (ra&7))<<3),
                      &Bl[(w*32 + i*8)*64]);
        }
        __syncthreads();
#pragma unroll
        for (int ks=0;ks<2;ks++){
            s16x8 af[4], bfr[4];
#pragma unroll
            for (int i=0;i<4;i++){
                const int ra = arow_base + i*16 + cc;
                const int rb = brow_base + i*16 + cc;
                af[i]  = *(const s16x8*)&Al[ra*64 + (((ks*4+g) ^ (ra&7))<<3)];
                bfr[i] = *(const s16x8*)&Bl[rb*64 + (((ks*4+g) ^ (rb&7))<<3)];
            }
#pragma unroll
            for (int i=0;i<4;i++)
#pragma unroll
                for (int j=0;j<4;j++)
                    acc[i][j] = MFMA(af[i], bfr[j], acc[i][j]);
        }
    }
#pragma unroll
    for (int j=0;j<4;j++){
        const int n = n0 + brow_base + j*16 + cc;
        const float bb = bvec[n];
#pragma unroll
        for (int i=0;i<4;i++){
            const int mb = m0 + arow_base + i*16 + g*4;
#pragma unroll
            for (int r=0;r<4;r++)
                out[(size_t)(mb+r)*768 + n] = acc[i][j][r] + bb;
        }
    }
}

// ---------------------------------------------------------------------------
// Flash attention: R10/R11 structure + double-buffered K/V/mask register
// prefetch. Per chunk: issue regs(c+1) + STAGE(c+1), wait vmcnt(20) -> both
// the next chunk's 10 reg loads AND its 10 DMAs stay in flight through this
// chunk's compute. Loop unroll 2 keeps the parity index compile-time.
// ---------------------------------------------------------------------------
__global__ __launch_bounds__(64, 2) void attn_mfma(
    const unsigned short* __restrict__ qs,   // [48][1024][64] bf16 (q*0.125)
    const unsigned short* __restrict__ kbf,  // [48][1024][64] bf16
    const unsigned short* __restrict__ vtf,  // [48][64][1024] bf16
    const float* __restrict__ kdyn,          // [48*1024][4][1024]
    const int*   __restrict__ kpm,           // [4][1024]
    const float* __restrict__ bias,          // [48][1024][1024]
    const float* __restrict__ red_w,         // [4][64]
    const float* __restrict__ red_b,         // [4]
    unsigned short* __restrict__ o)          // [4096][768] bf16
{
    __shared__ __align__(16) float kdL[2][2048];   // 2 x 8 KB
    __shared__ __align__(16) float bL[2][512];     // 2 x 2 KB

    const int lane = threadIdx.x & 63;
    const int bh = blockIdx.x, qt = blockIdx.y;
    const int b = bh / 12, h = bh % 12;
    const int t0 = qt*16;
    const int g = lane>>4, cc = lane&15;
    const int tq = t0 + cc;

    const unsigned short* qrow = qs + ((size_t)bh*1024 + tq)*64;
    s16x8 qf[2];
    qf[0] = *(const s16x8*)(qrow + g*8);
    qf[1] = *(const s16x8*)(qrow + 32 + g*8);

    float qred[4];
    {
        float pr[4] = {0.f,0.f,0.f,0.f};
#pragma unroll
        for (int ks=0; ks<2; ks++){
#pragma unroll
            for (int r=0;r<4;r++){
                float4 w0 = *(const float4*)(red_w + r*64 + 32*ks + 8*g);
                float4 w1 = *(const float4*)(red_w + r*64 + 32*ks + 8*g + 4);
                pr[r] += bf2f((unsigned short)qf[ks][0])*w0.x + bf2f((unsigned short)qf[ks][1])*w0.y
                       + bf2f((unsigned short)qf[ks][2])*w0.z + bf2f((unsigned short)qf[ks][3])*w0.w
                       + bf2f((unsigned short)qf[ks][4])*w1.x + bf2f((unsigned short)qf[ks][5])*w1.y
                       + bf2f((unsigned short)qf[ks][6])*w1.z + bf2f((unsigned short)qf[ks][7])*w1.w;
            }
        }
#pragma unroll
        for (int r=0;r<4;r++){
            pr[r] += __shfl_xor(pr[r], 16);
            pr[r] += __shfl_xor(pr[r], 32);
            qred[r] = pr[r]*8.f + red_b[r];
        }
    }

    f32x4 accO[4];
#pragma unroll
    for (int i=0;i<4;i++) accO[i] = (f32x4){0.f,0.f,0.f,0.f};
    float m_ = -1e30f, l_ = 0.f;

    const unsigned short* kcb = kbf + (size_t)bh*1024*64;
    const unsigned short* vcb = vtf + ((size_t)bh*64 + cc)*1024;
    const int* mp = kpm + b*1024 + 4*g;
    const size_t kd_row = (size_t)(bh*1024 + t0);

    const int r8_ = lane>>3, g8_ = lane&7;

    #define STAGE(buf_, c_) do {                                                  \
        const int s0_ = (c_)*32;                                                  \
        _Pragma("unroll")                                                         \
        for (int i_=0;i_<8;i_++){            /* kdyn rows rr=8i+r8 */             \
            const int rr_ = 8*i_ + r8_;                                           \
            const int t_ = rr_>>2, r_ = rr_&3;                                    \
            gld_lds16(kdyn + (kd_row + t_)*4096 + (size_t)r_*1024 + s0_           \
                          + ((g8_ ^ (t_&7))<<2),                                  \
                      &kdL[buf_][i_*256]);                                        \
        }                                                                         \
        _Pragma("unroll")                                                         \
        for (int i_=0;i_<2;i_++){            /* bias rows t=8i+r8 */              \
            const int t_ = 8*i_ + r8_;                                            \
            gld_lds16(bias + (kd_row + t_)*1024 + s0_ + ((g8_ ^ (t_&7))<<2),      \
                      &bL[buf_][i_*256]);                                         \
        }                                                                         \
    } while(0)

    #define REGLOAD(p_, c_) do {                                                  \
        const int s0n_ = (c_)*32;                                                 \
        _Pragma("unroll")                                                         \
        for (int sq_=0;sq_<2;sq_++){                                              \
            const unsigned short* kp_ = kcb + (size_t)(s0n_ + 16*sq_ + cc)*64 + g*8; \
            kfr[p_][sq_][0] = *(const s16x8*)(kp_);                               \
            kfr[p_][sq_][1] = *(const s16x8*)(kp_ + 32);                          \
        }                                                                         \
        _Pragma("unroll")                                                         \
        for (int dq_=0;dq_<4;dq_++)                                               \
            vfr[p_][dq_] = *(const s16x8*)(vcb + (size_t)dq_*16*1024 + s0n_ + 8*g); \
        mm0r[p_] = *(const int4*)(mp + s0n_);                                     \
        mm1r[p_] = *(const int4*)(mp + s0n_ + 16);                                \
    } while(0)

    s16x8 kfr[2][2][2];
    s16x8 vfr[2][4];
    int4 mm0r[2], mm1r[2];

    // ---- prologue: regs + stage for chunk 0
    REGLOAD(0, 0);
    STAGE(0, 0);

    const float NINF = -__builtin_inff();
    const int srcA = ((g&1)<<5) + cc;
    const int srcB = srcA + 16;
    const bool hi_half = (g>>1) != 0;

#pragma unroll 2
    for (int c = 0; c < 32; ++c) {
        const int pb = c & 1;

        // ---- issue next chunk's regs + DMAs; counted wait keeps them in flight
        if (c < 31){
            REGLOAD(pb^1, c+1);
            STAGE(pb^1, c+1);
            asm volatile("s_waitcnt vmcnt(20)" ::: "memory");
        } else {
            asm volatile("s_waitcnt vmcnt(0)" ::: "memory");
        }
        __builtin_amdgcn_sched_barrier(0);

        // ---- dyn tile from LDS: t=cc, s=16sq+4g+{0..3}
        float4 dyn[2];
#pragma unroll
        for (int sq=0;sq<2;sq++){
            const int slot = ((4*sq + g) ^ (cc&7)) << 2;
            float4 dv = *(const float4*)&bL[pb][cc*32 + slot];
            dv = fma4(qred[0], *(const float4*)&kdL[pb][(cc*4+0)*32 + slot], dv);
            dv = fma4(qred[1], *(const float4*)&kdL[pb][(cc*4+1)*32 + slot], dv);
            dv = fma4(qred[2], *(const float4*)&kdL[pb][(cc*4+2)*32 + slot], dv);
            dv = fma4(qred[3], *(const float4*)&kdL[pb][(cc*4+3)*32 + slot], dv);
            const int4 m4 = sq ? mm1r[pb] : mm0r[pb];
            dv.x = m4.x ? NINF : dv.x;
            dv.y = m4.y ? NINF : dv.y;
            dv.z = m4.z ? NINF : dv.z;
            dv.w = m4.w ? NINF : dv.w;
            dyn[sq] = dv;
        }

        // ---- QK^T (swapped): D[s_local=16sq+4g+r][q=cc]
        f32x4 sc[2];
        __builtin_amdgcn_s_setprio(1);
#pragma unroll
        for (int sq=0;sq<2;sq++){
            f32x4 z = (f32x4){0.f,0.f,0.f,0.f};
            z = MFMA(kfr[pb][sq][0], qf[0], z);
            z = MFMA(kfr[pb][sq][1], qf[1], z);
            sc[sq] = z;
        }
        __builtin_amdgcn_s_setprio(0);

        // ---- softmax (in-register; q=cc shared by 4 g-lanes)
        float v[8];
#pragma unroll
        for (int sq=0;sq<2;sq++){
            v[sq*4+0] = sc[sq][0] + dyn[sq].x;
            v[sq*4+1] = sc[sq][1] + dyn[sq].y;
            v[sq*4+2] = sc[sq][2] + dyn[sq].z;
            v[sq*4+3] = sc[sq][3] + dyn[sq].w;
        }
        float mx = v[0];
#pragma unroll
        for (int i=1;i<8;i++) mx = fmaxf(mx, v[i]);
        mx = fmaxf(mx, __shfl_xor(mx, 16));
        mx = fmaxf(mx, __shfl_xor(mx, 32));
        const float mn = fmaxf(m_, mx);
        float ps = 0.f;
#pragma unroll
        for (int i=0;i<8;i++){ v[i] = __expf(v[i]-mn); ps += v[i]; }
        ps += __shfl_xor(ps, 16);
        ps += __shfl_xor(ps, 32);
        const float scl = __expf(m_-mn);
        m_ = mn; l_ = l_*scl + ps;

        // ---- pack P, exchange -> PV A-fragment P[q=cc][s=8g+e]
        unsigned U[4] = { pk_bf16(v[0],v[1]), pk_bf16(v[2],v[3]),
                          pk_bf16(v[4],v[5]), pk_bf16(v[6],v[7]) };
        unsigned a0 = (unsigned)__shfl((int)U[0], srcA);
        unsigned a1 = (unsigned)__shfl((int)U[1], srcA);
        unsigned a2 = (unsigned)__shfl((int)U[2], srcA);
        unsigned a3 = (unsigned)__shfl((int)U[3], srcA);
        unsigned b0 = (unsigned)__shfl((int)U[0], srcB);
        unsigned b1 = (unsigned)__shfl((int)U[1], srcB);
        unsigned b2 = (unsigned)__shfl((int)U[2], srcB);
        unsigned b3 = (unsigned)__shfl((int)U[3], srcB);
        alignas(16) unsigned wv4[4] = { hi_half ? a2 : a0, hi_half ? a3 : a1,
                                        hi_half ? b2 : b0, hi_half ? b3 : b1 };
        s16x8 pa = *(const s16x8*)wv4;

        // ---- rescale accO (scl for q=4g+r lives at lane 20g+r)
        float sr[4];
#pragma unroll
        for (int r=0;r<4;r++) sr[r] = __shfl(scl, 20*g + r);
#pragma unroll
        for (int dq=0;dq<4;dq++){
            f32x4 a = accO[dq];
            a[0]*=sr[0]; a[1]*=sr[1]; a[2]*=sr[2]; a[3]*=sr[3];
            accO[dq] = a;
        }

        // ---- PV
        __builtin_amdgcn_s_setprio(1);
#pragma unroll
        for (int dq=0;dq<4;dq++)
            accO[dq] = MFMA(pa, vfr[pb][dq], accO[dq]);
        __builtin_amdgcn_s_setprio(0);
    }
    #undef STAGE
    #undef REGLOAD

    float linv[4];
#pragma unroll
    for (int r=0;r<4;r++) linv[r] = 1.0f / __shfl(l_, 20*g + r);
#pragma unroll
    for (int dq=0;dq<4;dq++){
#pragma unroll
        for (int r=0;r<4;r++){
            const int t = t0 + 4*g + r;
            o[(size_t)(b*1024 + t)*768 + h*64 + 16*dq + cc] = f2bf(accO[dq][r] * linv[r]);
        }
    }
}

extern "C" void kernel_launch(void* const* d_in, const int* in_sizes, int n_in,
                              void* d_out, int out_size, void* d_ws, size_t ws_size,
                              hipStream_t stream) {
    const float* query = (const float*)d_in[0];
    const float* kdyn  = (const float*)d_in[1];
    const int*   kpm   = (const int*)d_in[2];
    const float* bias  = (const float*)d_in[3];
    const float* in_w  = (const float*)d_in[4];
    const float* in_b  = (const float*)d_in[5];
    const float* red_w = (const float*)d_in[6];
    const float* red_b = (const float*)d_in[7];
    const float* out_w = (const float*)d_in[8];
    const float* out_b = (const float*)d_in[9];
    float* out = (float*)d_out;

    const size_t SEG = (size_t)48*1024*64;           // 3,145,728 elems
    unsigned short* qs  = (unsigned short*)d_ws;
    unsigned short* kb  = qs + SEG;
    unsigned short* vt  = kb + SEG;
    unsigned short* ob  = vt + SEG;                  // [4096][768] bf16
    unsigned short* qb  = ob + SEG;                  // query bf16 [4096][768]
    unsigned short* wqb = qb + SEG;                  // in_w bf16 [2304][768]
    unsigned short* wob = wqb + (size_t)2304*768;    // out_w bf16 [768][768]

    const int n0 = (4096*768)/8;    // 393216
    const int n1 = (2304*768)/8;    // 221184
    const int n2 = (768*768)/8;     //  73728
    cvt3<<<dim3((n0+n1+n2+255)/256), 256, 0, stream>>>(
        query, qb, n0, in_w, wqb, n1, out_w, wob, n2);

    gemm_qkv_bf16<<<dim3(18,32), 256, 0, stream>>>(qb, wqb, in_b, qs, kb, vt);
    attn_mfma<<<dim3(48,64), 64, 0, stream>>>(qs, kb, vt, kdyn, kpm, bias, red_w, red_b, ob);
    gemm_obf_bf16<<<dim3(6,32), 256, 0, stream>>>(ob, wob, out_b, out);
}